// Round 1
// baseline (368.493 us; speedup 1.0000x reference)
//
#include <hip/hip_runtime.h>
#include <hip/hip_bf16.h>

// Fused 3-stage strided conv1d encoder.
// x: [B,1,16384] fp32, three convs K=6 stride=2 VALID:
//   L1 = 8190, L2 = 4093, L3 = 2044.
// One thread computes one final output element directly from x:
//   out[r, j3] needs x[r, 8*j3 .. 8*j3+35]  (36 floats, 9 aligned float4).
// Memory-bound: 268 MB read + 33.5 MB write => ~48 us floor at 6.3 TB/s.

#define L_IN  16384
#define L1    8190
#define L2    4093
#define L3    2044
#define KW    6

__global__ __launch_bounds__(256) void encoder_fused_kernel(
    const float* __restrict__ x,
    const float* __restrict__ w1, const float* __restrict__ b1,
    const float* __restrict__ w2, const float* __restrict__ b2,
    const float* __restrict__ w3, const float* __restrict__ b3,
    float* __restrict__ out)
{
    const int j3 = blockIdx.x * blockDim.x + threadIdx.x;
    const int row = blockIdx.y;
    if (j3 >= L3) return;

    // Load weights (uniform across wave -> scalar-cached loads)
    float W1[KW], W2[KW], W3[KW];
#pragma unroll
    for (int t = 0; t < KW; ++t) { W1[t] = w1[t]; W2[t] = w2[t]; W3[t] = w3[t]; }
    const float B1 = b1[0], B2 = b2[0], B3 = b3[0];

    // 36-float window, 9 aligned float4 loads (8*j3 floats = 32B aligned)
    const float* xr = x + (size_t)row * L_IN + 8 * (size_t)j3;
    float v[36];
    const float4* xv = reinterpret_cast<const float4*>(xr);
#pragma unroll
    for (int i = 0; i < 9; ++i) {
        float4 t = xv[i];
        v[4 * i + 0] = t.x;
        v[4 * i + 1] = t.y;
        v[4 * i + 2] = t.z;
        v[4 * i + 3] = t.w;
    }

    // conv1: 16 outputs (relative indices), stride 2 over v
    float c1[16];
#pragma unroll
    for (int i = 0; i < 16; ++i) {
        float s = B1;
#pragma unroll
        for (int t = 0; t < KW; ++t) s = fmaf(W1[t], v[2 * i + t], s);
        c1[i] = s;
    }

    // conv2: 6 outputs, stride 2 over c1
    float c2[KW];
#pragma unroll
    for (int i = 0; i < KW; ++i) {
        float s = B2;
#pragma unroll
        for (int t = 0; t < KW; ++t) s = fmaf(W2[t], c1[2 * i + t], s);
        c2[i] = s;
    }

    // conv3: 1 output
    float o = B3;
#pragma unroll
    for (int t = 0; t < KW; ++t) o = fmaf(W3[t], c2[t], o);

    out[(size_t)row * L3 + j3] = o;
}

extern "C" void kernel_launch(void* const* d_in, const int* in_sizes, int n_in,
                              void* d_out, int out_size, void* d_ws, size_t ws_size,
                              hipStream_t stream) {
    const float* x  = (const float*)d_in[0];
    const float* w1 = (const float*)d_in[1];
    const float* b1 = (const float*)d_in[2];
    const float* w2 = (const float*)d_in[3];
    const float* b2 = (const float*)d_in[4];
    const float* w3 = (const float*)d_in[5];
    const float* b3 = (const float*)d_in[6];
    float* out = (float*)d_out;

    const int B = in_sizes[0] / L_IN;  // 4096

    dim3 block(256);
    dim3 grid((L3 + 255) / 256, B);  // (8, 4096)
    encoder_fused_kernel<<<grid, block, 0, stream>>>(x, w1, b1, w2, b2, w3, b3, out);
}